// Round 16
// baseline (270.761 us; speedup 1.0000x reference)
//
#include <hip/hip_runtime.h>

typedef unsigned int u32;
typedef unsigned short u16;
typedef __attribute__((ext_vector_type(4))) float fx4;
typedef __attribute__((ext_vector_type(8))) short s16x8;
typedef __attribute__((ext_vector_type(4))) u32 u32x4;

#define DD 128
#define KK 1024

__device__ __forceinline__ u16 f2bf(float f) {
  u32 u = __float_as_uint(f);
  return (u16)((u + 0x7FFFu + ((u >> 16) & 1u)) >> 16);
}
__device__ __forceinline__ u32 umin32(u32 a, u32 b) { return a < b ? a : b; }

// packed bf16 RNE convert: bf16(lo) -> bits[15:0], bf16(hi) -> bits[31:16]
__device__ __forceinline__ u32 cvtpk(float lo, float hi) {
  u32 r;
  asm("v_cvt_pk_bf16_f32 %0, %1, %2" : "=v"(r) : "v"(lo), "v"(hi));
  return r;
}
// same, with free VOP3 neg modifiers on both inputs
__device__ __forceinline__ u32 cvtpkn(float lo, float hi) {
  u32 r;
  asm("v_cvt_pk_bf16_f32 %0, -%1, -%2" : "=v"(r) : "v"(lo), "v"(hi));
  return r;
}
__device__ __forceinline__ s16x8 as_s16x8(u32x4 v) {
  union { u32x4 u; s16x8 s; } x;
  x.u = v;
  return x.s;
}

// ---------------- prep: cbf fp32 -> bf16 (RTN, bit-identical to prior rounds),
// k-major cbt: [lvl(4)][ku(16)][col(1024)][8] u16 (1 MiB). 256 blocks x 64 thr,
// block = 16 codewords. Also zeroes the loss slot in d_out. (unchanged)
extern "C" __global__ __launch_bounds__(64) void rvq_prep(
    const float* __restrict__ cbf, u16* __restrict__ cbt,
    float* __restrict__ lossout) {
  if (blockIdx.x == 0 && threadIdx.x == 0) lossout[0] = 0.f;
  const int cl = threadIdx.x >> 2, dq = threadIdx.x & 3;
  const int cw = blockIdx.x * 16 + cl;
  const int lvl = cw >> 10, colg = cw & 1023;
  const float* src = cbf + (size_t)cw * DD + dq * 32;
  u32x4* dst = (u32x4*)cbt;
#pragma unroll
  for (int k8 = 0; k8 < 4; ++k8) {
    const fx4 a = *(const fx4*)(src + k8 * 8);
    const fx4 b = *(const fx4*)(src + k8 * 8 + 4);
    u32x4 pk;
    pk.x = (u32)f2bf(a[0]) | ((u32)f2bf(a[1]) << 16);
    pk.y = (u32)f2bf(a[2]) | ((u32)f2bf(a[3]) << 16);
    pk.z = (u32)f2bf(b[0]) | ((u32)f2bf(b[1]) << 16);
    pk.w = (u32)f2bf(b[2]) | ((u32)f2bf(b[3]) << 16);
    dst[((lvl * 16 + dq * 4 + k8) * 1024) + colg] = pk;  // 1 KB-coalesced across block
  }
}

// ---------------- main: 512 blocks x 256 thr; block = 64 rows x 1024 cols.
// CHAMPION r13 (72us: depth-3 prefetch + Xlds + isolated setprio, clean
// traffic) + ONE zero-traffic change: EARLY brA ISSUE at level boundaries.
// r13 loads each level's first B-block at the level top, exposing its full
// L2 latency at KSTEP0 while the preceding ~1500-2500 cyc reduce/update/
// rebuild phase ran with an idle memory pipe. Here: right after KSTEP15's
// flush (all 4 buffers dead), issue the NEXT level's brA (block rot); its
// latency hides under the boundary phase. brB/brC stay at level top —
// consumed >=1 KSTEP (~2600 cyc) later, already covered.
// vs r8 (which spilled doing similar): r8's cln pointer + dual-pointer
// select were live through ALL 16 KSTEPs; here the KSTEP macro is
// byte-identical to r13 and only a 4-load block is added at the boundary.
// Added liveness = brA (16 regs) across reduce/rebuild; peak rebuild
// pressure ~ afr 64 + brA 16 + temps ~ 110 < 128 budget.
// Hypothesis ledger (all measured): r4 depth 1->3 +6.5%; r7 more-waves
// null; r13 setprio +10%; r14 hand-counted vmcnt neutral (drain refuted);
// r15 split-acc chains negative (chain-latency refuted, vgpr>128 cliff);
// r1/2/6 bound-spill; r3 tile tail; r5/r8/r11 spill at 128-budget;
// r9 LDS-staging anomaly; r10 172-reg occupancy cliff.
extern "C" __global__ __launch_bounds__(256, 2) void rvq_main(
    const float* __restrict__ x, const float* __restrict__ cbf,
    const u16* __restrict__ cbt, float* __restrict__ yout,
    float* __restrict__ lossacc) {
  __shared__ float Rlds[64][132];  // negated residual, single copy; +4 pad
  __shared__ float Xlds[64][132];  // raw x tile (final level: y = x + R)
  __shared__ u32 lmin[64][4];      // [row][wave]

  const int tid = threadIdx.x;
  const int wv = tid >> 6, lane = tid & 63;
  const int c = lane & 15, q = lane >> 4;
  const int rowbase = blockIdx.x * 64;
  const int rot = (int)((blockIdx.x >> 3) & 15);  // de-lockstep same-XCD L2 streams
  const s16x8* cbt16 = (const s16x8*)cbt;         // 16B units: [lvl][ku][col]

  s16x8 afr[4][4];  // A-frags: afr[t][s] -> rows t*16+c, k = s*32 + q*8 + j
#pragma unroll
  for (int t = 0; t < 4; ++t) {
    const float* xr = x + (size_t)(rowbase + t * 16 + c) * DD + q * 8;
#pragma unroll
    for (int s = 0; s < 4; ++s) {
      const fx4 a = *(const fx4*)(xr + s * 32);
      const fx4 b = *(const fx4*)(xr + s * 32 + 4);
      u32x4 af;
      af.x = cvtpkn(a[0], a[1]);
      af.y = cvtpkn(a[2], a[3]);
      af.z = cvtpkn(b[0], b[1]);
      af.w = cvtpkn(b[2], b[3]);
      afr[t][s] = as_s16x8(af);
      if (t == wv) {  // wave wv owns rows wv*16..wv*16+15 of Rlds AND Xlds
        fx4 na, nb;
#pragma unroll
        for (int j = 0; j < 4; ++j) { na[j] = -a[j]; nb[j] = -b[j]; }
        *(fx4*)&Rlds[t * 16 + c][s * 32 + q * 8] = na;
        *(fx4*)&Rlds[t * 16 + c][s * 32 + q * 8 + 4] = nb;
        *(fx4*)&Xlds[t * 16 + c][s * 32 + q * 8] = a;
        *(fx4*)&Xlds[t * 16 + c][s * 32 + q * 8 + 4] = b;
      }
    }
  }

  u32 run[4][4];
#pragma unroll
  for (int t = 0; t < 4; ++t)
#pragma unroll
    for (int r = 0; r < 4; ++r) run[t][r] = 0xFFFFFFFFu;

  float lsum = 0.f;

  // Rotating B buffers, hoisted so brA can carry across level boundaries.
  s16x8 brA[4], brB[4], brC[4], brD[4];

#pragma unroll 1
  for (int lvl = 0; lvl < 4; ++lvl) {
    const s16x8* cl = cbt16 + lvl * 16384 + q * 1024 + c;  // + s*4096 + colbase
    {
      // lvl==0: warm-start brA here. lvl>0: brA was early-issued at the
      // previous level's boundary (latency hidden under reduce/rebuild).
      if (lvl == 0) {
        const int cb0 = ((rot) & 15) * 64 + wv * 16;
#pragma unroll
        for (int s5 = 0; s5 < 4; ++s5) brA[s5] = cl[s5 * 4096 + cb0];
      }
      const int cb1 = (((rot + 1) & 15) * 64) + wv * 16;
      const int cb2 = (((rot + 2) & 15) * 64) + wv * 16;
#pragma unroll
      for (int s5 = 0; s5 < 4; ++s5) {
        brB[s5] = cl[s5 * 4096 + cb1];
        brC[s5] = cl[s5 * 4096 + cb2];
      }
    }
    // acc = 0.75 - r.c  in (0.625, 0.875) [|r.c| <= ~0.04 here, wrap-safe to 0.125]
    // key = (bits(acc)<<10) + col - 2^31 : monotone, ties -> lowest col.
    // Buffer rotation (depth 3): step CT consumes buffer CT%4, prefetches
    // column-block CT+3 into buffer (CT+3)%4 (free since CT-1).
#define KSTEP(CUR, NXT, CT)                                                        \
  {                                                                                \
    if ((CT) < 13) {                                                               \
      const int cbn = ((((CT) + 3 + rot) & 15) * 64) + wv * 16;                    \
      _Pragma("unroll") for (int s5 = 0; s5 < 4; ++s5)                             \
          NXT[s5] = cl[s5 * 4096 + cbn];                                           \
    }                                                                              \
    const u32 kadd = (u32)(((((CT) + rot) & 15) * 64) + wv * 16 + c) - 0x80000000u;\
    fx4 ac0 = {0.75f, 0.75f, 0.75f, 0.75f};                                        \
    fx4 ac1 = ac0, ac2 = ac0, ac3 = ac0;                                           \
    __builtin_amdgcn_s_setprio(1);                                                 \
    _Pragma("unroll") for (int s5 = 0; s5 < 4; ++s5) {                             \
      const s16x8 bfrag = CUR[s5];                                                 \
      ac0 = __builtin_amdgcn_mfma_f32_16x16x32_bf16(afr[0][s5], bfrag, ac0, 0, 0, 0); \
      ac1 = __builtin_amdgcn_mfma_f32_16x16x32_bf16(afr[1][s5], bfrag, ac1, 0, 0, 0); \
      ac2 = __builtin_amdgcn_mfma_f32_16x16x32_bf16(afr[2][s5], bfrag, ac2, 0, 0, 0); \
      ac3 = __builtin_amdgcn_mfma_f32_16x16x32_bf16(afr[3][s5], bfrag, ac3, 0, 0, 0); \
    }                                                                              \
    __builtin_amdgcn_s_setprio(0);                                                 \
    _Pragma("unroll") for (int r5 = 0; r5 < 4; ++r5) {                             \
      run[0][r5] = umin32(run[0][r5], (__float_as_uint(ac0[r5]) << 10) + kadd);    \
      run[1][r5] = umin32(run[1][r5], (__float_as_uint(ac1[r5]) << 10) + kadd);    \
      run[2][r5] = umin32(run[2][r5], (__float_as_uint(ac2[r5]) << 10) + kadd);    \
      run[3][r5] = umin32(run[3][r5], (__float_as_uint(ac3[r5]) << 10) + kadd);    \
    }                                                                              \
  }
    KSTEP(brA, brD, 0)  KSTEP(brB, brA, 1)  KSTEP(brC, brB, 2)  KSTEP(brD, brC, 3)
    KSTEP(brA, brD, 4)  KSTEP(brB, brA, 5)  KSTEP(brC, brB, 6)  KSTEP(brD, brC, 7)
    KSTEP(brA, brD, 8)  KSTEP(brB, brA, 9)  KSTEP(brC, brB, 10) KSTEP(brD, brC, 11)
    KSTEP(brA, brD, 12) KSTEP(brB, brA, 13) KSTEP(brC, brB, 14) KSTEP(brD, brC, 15)
#undef KSTEP

    // boundary: all 4 buffers dead — early-issue NEXT level's brA so its L2
    // latency hides under the reduce/update/rebuild phase below.
    if (lvl < 3) {
      const s16x8* cln2 = cl + 16384;
      const int cb0 = ((rot) & 15) * 64 + wv * 16;
#pragma unroll
      for (int s5 = 0; s5 < 4; ++s5) brA[s5] = cln2[s5 * 4096 + cb0];
    }

    // reduce over the 16 c-lanes (row lives on q*4+r within tile t)
#pragma unroll
    for (int m = 1; m < 16; m <<= 1)
#pragma unroll
      for (int t = 0; t < 4; ++t)
#pragma unroll
        for (int r = 0; r < 4; ++r)
          run[t][r] = umin32(run[t][r], (u32)__shfl_xor((int)run[t][r], m, 64));
    if (c == 0) {
#pragma unroll
      for (int t = 0; t < 4; ++t)
#pragma unroll
        for (int r = 0; r < 4; ++r)
          lmin[t * 16 + q * 4 + r][wv] = run[t][r];
    }
    __syncthreads();  // lmin complete across the 4 waves

    // update own rows: row = wv*16 + c, dims q*32..q*32+31 (exact fp32 codebook)
    const int row = wv * 16 + c;
    const u32x4 p = *(const u32x4*)&lmin[row][0];
    const u32 pm = umin32(umin32(p.x, p.y), umin32(p.z, p.w));
    const int col = (int)(pm & 1023u);
    const float* qp = cbf + ((size_t)lvl * KK + col) * DD + q * 32;
    float* Rr = &Rlds[row][q * 32];
    if (lvl < 3) {
#pragma unroll
      for (int k4 = 0; k4 < 8; ++k4) {
        fx4 rv = *(const fx4*)(Rr + k4 * 4);
        const fx4 qv = *(const fx4*)(qp + k4 * 4);
#pragma unroll
        for (int j = 0; j < 4; ++j) { rv[j] += qv[j]; lsum = fmaf(rv[j], rv[j], lsum); }
        *(fx4*)(Rr + k4 * 4) = rv;
      }
      __syncthreads();  // new residual visible; also orders lmin reads vs next level
      // rebuild all 64 rows' A-frags from Rlds; reset keys
#pragma unroll
      for (int t = 0; t < 4; ++t)
#pragma unroll
        for (int s = 0; s < 4; ++s) {
          const fx4 r0 = *(const fx4*)&Rlds[t * 16 + c][s * 32 + q * 8];
          const fx4 r1 = *(const fx4*)&Rlds[t * 16 + c][s * 32 + q * 8 + 4];
          u32x4 af;
          af.x = cvtpk(r0[0], r0[1]);
          af.y = cvtpk(r0[2], r0[3]);
          af.z = cvtpk(r1[0], r1[1]);
          af.w = cvtpk(r1[2], r1[3]);
          afr[t][s] = as_s16x8(af);
        }
#pragma unroll
      for (int t = 0; t < 4; ++t)
#pragma unroll
        for (int r = 0; r < 4; ++r) run[t][r] = 0xFFFFFFFFu;
    } else {  // final level: y = x + R_final (forward value = q_sum), x from Xlds
      const size_t gb = (size_t)(rowbase + row) * DD + q * 32;
      const float* Xr = &Xlds[row][q * 32];
#pragma unroll
      for (int k4 = 0; k4 < 8; ++k4) {
        fx4 rv = *(const fx4*)(Rr + k4 * 4);
        const fx4 qv = *(const fx4*)(qp + k4 * 4);
        const fx4 xv = *(const fx4*)(Xr + k4 * 4);
        fx4 yv;
#pragma unroll
        for (int j = 0; j < 4; ++j) {
          rv[j] += qv[j];
          lsum = fmaf(rv[j], rv[j], lsum);
          yv[j] = xv[j] + rv[j];
        }
        *(fx4*)(yout + gb + k4 * 4) = yv;
      }
    }
  }

#pragma unroll
  for (int m = 32; m >= 1; m >>= 1) lsum += __shfl_xor(lsum, m, 64);
  if (lane == 0) atomicAdd(lossacc, lsum * (1.25f / 4194304.f));  // 1.25/(N*D)
}

extern "C" void kernel_launch(void* const* d_in, const int* in_sizes, int n_in,
                              void* d_out, int out_size, void* d_ws, size_t ws_size,
                              hipStream_t stream) {
  const float* x = (const float*)d_in[0];     // [32768,128]
  const float* cbf = (const float*)d_in[1];   // [4,1024,128]
  float* y = (float*)d_out;
  float* lossout = y + (out_size - 1);
  u16* cbt = (u16*)d_ws;                      // 1 MiB k-major bf16 codebook

  rvq_prep<<<256, 64, 0, stream>>>(cbf, cbt, lossout);
  rvq_main<<<512, 256, 0, stream>>>(x, cbf, cbt, y, lossout);
}

// Round 17
// 136.491 us; speedup vs baseline: 1.9837x; 1.9837x over previous
//
#include <hip/hip_runtime.h>

typedef unsigned int u32;
typedef unsigned short u16;
typedef __attribute__((ext_vector_type(4))) float fx4;
typedef __attribute__((ext_vector_type(8))) short s16x8;
typedef __attribute__((ext_vector_type(4))) u32 u32x4;

#define DD 128
#define KK 1024

__device__ __forceinline__ u16 f2bf(float f) {
  u32 u = __float_as_uint(f);
  return (u16)((u + 0x7FFFu + ((u >> 16) & 1u)) >> 16);
}
__device__ __forceinline__ u32 umin32(u32 a, u32 b) { return a < b ? a : b; }

// packed bf16 RNE convert: bf16(lo) -> bits[15:0], bf16(hi) -> bits[31:16]
__device__ __forceinline__ u32 cvtpk(float lo, float hi) {
  u32 r;
  asm("v_cvt_pk_bf16_f32 %0, %1, %2" : "=v"(r) : "v"(lo), "v"(hi));
  return r;
}
// same, with free VOP3 neg modifiers on both inputs
__device__ __forceinline__ u32 cvtpkn(float lo, float hi) {
  u32 r;
  asm("v_cvt_pk_bf16_f32 %0, -%1, -%2" : "=v"(r) : "v"(lo), "v"(hi));
  return r;
}
__device__ __forceinline__ s16x8 as_s16x8(u32x4 v) {
  union { u32x4 u; s16x8 s; } x;
  x.u = v;
  return x.s;
}

// ---------------- prep: cbf fp32 -> bf16 (RTN, bit-identical to prior rounds),
// k-major cbt: [lvl(4)][ku(16)][col(1024)][8] u16 (1 MiB). 256 blocks x 64 thr,
// block = 16 codewords. Also zeroes the loss slot in d_out. (unchanged)
extern "C" __global__ __launch_bounds__(64) void rvq_prep(
    const float* __restrict__ cbf, u16* __restrict__ cbt,
    float* __restrict__ lossout) {
  if (blockIdx.x == 0 && threadIdx.x == 0) lossout[0] = 0.f;
  const int cl = threadIdx.x >> 2, dq = threadIdx.x & 3;
  const int cw = blockIdx.x * 16 + cl;
  const int lvl = cw >> 10, colg = cw & 1023;
  const float* src = cbf + (size_t)cw * DD + dq * 32;
  u32x4* dst = (u32x4*)cbt;
#pragma unroll
  for (int k8 = 0; k8 < 4; ++k8) {
    const fx4 a = *(const fx4*)(src + k8 * 8);
    const fx4 b = *(const fx4*)(src + k8 * 8 + 4);
    u32x4 pk;
    pk.x = (u32)f2bf(a[0]) | ((u32)f2bf(a[1]) << 16);
    pk.y = (u32)f2bf(a[2]) | ((u32)f2bf(a[3]) << 16);
    pk.z = (u32)f2bf(b[0]) | ((u32)f2bf(b[1]) << 16);
    pk.w = (u32)f2bf(b[2]) | ((u32)f2bf(b[3]) << 16);
    dst[((lvl * 16 + dq * 4 + k8) * 1024) + colg] = pk;  // 1 KB-coalesced across block
  }
}

// ---------------- main: 512 blocks x 256 thr; block = 64 rows x 1024 cols.
// FINAL CHAMPION (r13, 72.0us main / 137.4us bench): r4 structure (depth-3
// register prefetch, Xlds, clean compulsory traffic, VGPR=128 no spill,
// 2 blocks/CU) + isolated s_setprio(1..0) around the 16-MFMA cluster (+10%,
// the one clean scheduling win of the session).
//
// CONSTRAINT SURFACE — measured, all axes refuted at least once:
//  - prefetch: depth 1->3 +6.5% (r4); hand-counted vmcnt neutral (r14) —
//    load latency is covered, not the wall.
//  - TLP: clean 8-wave row-split (r7, VGPR=100) -38% (2x codebook streams);
//    smaller tiles (r3) add a residency tail; min-waves>=3 bounds spill
//    (r1/r2/r6). 8 waves/CU is this shape's ceiling.
//  - regs >128: r10 (172) and r15 (148) both hit the m69 occupancy cliff
//    (waves halve at 128) — net negative despite per-wave gains.
//  - regs +eps at the 128 budget: r5/r8/r11/r16 ALL spill — the boundary
//    reduce/update/rebuild phase has ZERO register headroom; nothing may
//    be live across it (afr 64 + rebuild temps saturate the budget).
//  - MFMA chain ILP: split-acc (r15) refuted — issue spacing >= dep latency.
//  - LDS staging: r9/r11 large regressions (barriers, write-policy anomaly).
// Residual: ~1500 cyc/KSTEP stall, unattributable with available counters;
// FETCH 20.8 / WRITE 17.5 MB = compulsory traffic; MfmaUtil ~18%.
extern "C" __global__ __launch_bounds__(256, 2) void rvq_main(
    const float* __restrict__ x, const float* __restrict__ cbf,
    const u16* __restrict__ cbt, float* __restrict__ yout,
    float* __restrict__ lossacc) {
  __shared__ float Rlds[64][132];  // negated residual, single copy; +4 pad
  __shared__ float Xlds[64][132];  // raw x tile (final level: y = x + R)
  __shared__ u32 lmin[64][4];      // [row][wave]

  const int tid = threadIdx.x;
  const int wv = tid >> 6, lane = tid & 63;
  const int c = lane & 15, q = lane >> 4;
  const int rowbase = blockIdx.x * 64;
  const int rot = (int)((blockIdx.x >> 3) & 15);  // de-lockstep same-XCD L2 streams
  const s16x8* cbt16 = (const s16x8*)cbt;         // 16B units: [lvl][ku][col]

  s16x8 afr[4][4];  // A-frags: afr[t][s] -> rows t*16+c, k = s*32 + q*8 + j
#pragma unroll
  for (int t = 0; t < 4; ++t) {
    const float* xr = x + (size_t)(rowbase + t * 16 + c) * DD + q * 8;
#pragma unroll
    for (int s = 0; s < 4; ++s) {
      const fx4 a = *(const fx4*)(xr + s * 32);
      const fx4 b = *(const fx4*)(xr + s * 32 + 4);
      u32x4 af;
      af.x = cvtpkn(a[0], a[1]);
      af.y = cvtpkn(a[2], a[3]);
      af.z = cvtpkn(b[0], b[1]);
      af.w = cvtpkn(b[2], b[3]);
      afr[t][s] = as_s16x8(af);
      if (t == wv) {  // wave wv owns rows wv*16..wv*16+15 of Rlds AND Xlds
        fx4 na, nb;
#pragma unroll
        for (int j = 0; j < 4; ++j) { na[j] = -a[j]; nb[j] = -b[j]; }
        *(fx4*)&Rlds[t * 16 + c][s * 32 + q * 8] = na;
        *(fx4*)&Rlds[t * 16 + c][s * 32 + q * 8 + 4] = nb;
        *(fx4*)&Xlds[t * 16 + c][s * 32 + q * 8] = a;
        *(fx4*)&Xlds[t * 16 + c][s * 32 + q * 8 + 4] = b;
      }
    }
  }

  u32 run[4][4];
#pragma unroll
  for (int t = 0; t < 4; ++t)
#pragma unroll
    for (int r = 0; r < 4; ++r) run[t][r] = 0xFFFFFFFFu;

  float lsum = 0.f;

#pragma unroll 1
  for (int lvl = 0; lvl < 4; ++lvl) {
    const s16x8* cl = cbt16 + lvl * 16384 + q * 1024 + c;  // + s*4096 + colbase
    s16x8 brA[4], brB[4], brC[4], brD[4];
    {
      const int cb0 = ((rot) & 15) * 64 + wv * 16;
      const int cb1 = (((rot + 1) & 15) * 64) + wv * 16;
      const int cb2 = (((rot + 2) & 15) * 64) + wv * 16;
#pragma unroll
      for (int s5 = 0; s5 < 4; ++s5) {
        brA[s5] = cl[s5 * 4096 + cb0];
        brB[s5] = cl[s5 * 4096 + cb1];
        brC[s5] = cl[s5 * 4096 + cb2];
      }
    }
    // acc = 0.75 - r.c  in (0.625, 0.875) [|r.c| <= ~0.04 here, wrap-safe to 0.125]
    // key = (bits(acc)<<10) + col - 2^31 : monotone, ties -> lowest col.
    // Buffer rotation (depth 3): step CT consumes buffer CT%4, prefetches
    // column-block CT+3 into buffer (CT+3)%4 (free since CT-1).
#define KSTEP(CUR, NXT, CT)                                                        \
  {                                                                                \
    if ((CT) < 13) {                                                               \
      const int cbn = ((((CT) + 3 + rot) & 15) * 64) + wv * 16;                    \
      _Pragma("unroll") for (int s5 = 0; s5 < 4; ++s5)                             \
          NXT[s5] = cl[s5 * 4096 + cbn];                                           \
    }                                                                              \
    const u32 kadd = (u32)(((((CT) + rot) & 15) * 64) + wv * 16 + c) - 0x80000000u;\
    fx4 ac0 = {0.75f, 0.75f, 0.75f, 0.75f};                                        \
    fx4 ac1 = ac0, ac2 = ac0, ac3 = ac0;                                           \
    __builtin_amdgcn_s_setprio(1);                                                 \
    _Pragma("unroll") for (int s5 = 0; s5 < 4; ++s5) {                             \
      const s16x8 bfrag = CUR[s5];                                                 \
      ac0 = __builtin_amdgcn_mfma_f32_16x16x32_bf16(afr[0][s5], bfrag, ac0, 0, 0, 0); \
      ac1 = __builtin_amdgcn_mfma_f32_16x16x32_bf16(afr[1][s5], bfrag, ac1, 0, 0, 0); \
      ac2 = __builtin_amdgcn_mfma_f32_16x16x32_bf16(afr[2][s5], bfrag, ac2, 0, 0, 0); \
      ac3 = __builtin_amdgcn_mfma_f32_16x16x32_bf16(afr[3][s5], bfrag, ac3, 0, 0, 0); \
    }                                                                              \
    __builtin_amdgcn_s_setprio(0);                                                 \
    _Pragma("unroll") for (int r5 = 0; r5 < 4; ++r5) {                             \
      run[0][r5] = umin32(run[0][r5], (__float_as_uint(ac0[r5]) << 10) + kadd);    \
      run[1][r5] = umin32(run[1][r5], (__float_as_uint(ac1[r5]) << 10) + kadd);    \
      run[2][r5] = umin32(run[2][r5], (__float_as_uint(ac2[r5]) << 10) + kadd);    \
      run[3][r5] = umin32(run[3][r5], (__float_as_uint(ac3[r5]) << 10) + kadd);    \
    }                                                                              \
  }
    KSTEP(brA, brD, 0)  KSTEP(brB, brA, 1)  KSTEP(brC, brB, 2)  KSTEP(brD, brC, 3)
    KSTEP(brA, brD, 4)  KSTEP(brB, brA, 5)  KSTEP(brC, brB, 6)  KSTEP(brD, brC, 7)
    KSTEP(brA, brD, 8)  KSTEP(brB, brA, 9)  KSTEP(brC, brB, 10) KSTEP(brD, brC, 11)
    KSTEP(brA, brD, 12) KSTEP(brB, brA, 13) KSTEP(brC, brB, 14) KSTEP(brD, brC, 15)
#undef KSTEP

    // reduce over the 16 c-lanes (row lives on q*4+r within tile t)
#pragma unroll
    for (int m = 1; m < 16; m <<= 1)
#pragma unroll
      for (int t = 0; t < 4; ++t)
#pragma unroll
        for (int r = 0; r < 4; ++r)
          run[t][r] = umin32(run[t][r], (u32)__shfl_xor((int)run[t][r], m, 64));
    if (c == 0) {
#pragma unroll
      for (int t = 0; t < 4; ++t)
#pragma unroll
        for (int r = 0; r < 4; ++r)
          lmin[t * 16 + q * 4 + r][wv] = run[t][r];
    }
    __syncthreads();  // lmin complete across the 4 waves

    // update own rows: row = wv*16 + c, dims q*32..q*32+31 (exact fp32 codebook)
    const int row = wv * 16 + c;
    const u32x4 p = *(const u32x4*)&lmin[row][0];
    const u32 pm = umin32(umin32(p.x, p.y), umin32(p.z, p.w));
    const int col = (int)(pm & 1023u);
    const float* qp = cbf + ((size_t)lvl * KK + col) * DD + q * 32;
    float* Rr = &Rlds[row][q * 32];
    if (lvl < 3) {
#pragma unroll
      for (int k4 = 0; k4 < 8; ++k4) {
        fx4 rv = *(const fx4*)(Rr + k4 * 4);
        const fx4 qv = *(const fx4*)(qp + k4 * 4);
#pragma unroll
        for (int j = 0; j < 4; ++j) { rv[j] += qv[j]; lsum = fmaf(rv[j], rv[j], lsum); }
        *(fx4*)(Rr + k4 * 4) = rv;
      }
      __syncthreads();  // new residual visible; also orders lmin reads vs next level
      // rebuild all 64 rows' A-frags from Rlds; reset keys
#pragma unroll
      for (int t = 0; t < 4; ++t)
#pragma unroll
        for (int s = 0; s < 4; ++s) {
          const fx4 r0 = *(const fx4*)&Rlds[t * 16 + c][s * 32 + q * 8];
          const fx4 r1 = *(const fx4*)&Rlds[t * 16 + c][s * 32 + q * 8 + 4];
          u32x4 af;
          af.x = cvtpk(r0[0], r0[1]);
          af.y = cvtpk(r0[2], r0[3]);
          af.z = cvtpk(r1[0], r1[1]);
          af.w = cvtpk(r1[2], r1[3]);
          afr[t][s] = as_s16x8(af);
        }
#pragma unroll
      for (int t = 0; t < 4; ++t)
#pragma unroll
        for (int r = 0; r < 4; ++r) run[t][r] = 0xFFFFFFFFu;
    } else {  // final level: y = x + R_final (forward value = q_sum), x from Xlds
      const size_t gb = (size_t)(rowbase + row) * DD + q * 32;
      const float* Xr = &Xlds[row][q * 32];
#pragma unroll
      for (int k4 = 0; k4 < 8; ++k4) {
        fx4 rv = *(const fx4*)(Rr + k4 * 4);
        const fx4 qv = *(const fx4*)(qp + k4 * 4);
        const fx4 xv = *(const fx4*)(Xr + k4 * 4);
        fx4 yv;
#pragma unroll
        for (int j = 0; j < 4; ++j) {
          rv[j] += qv[j];
          lsum = fmaf(rv[j], rv[j], lsum);
          yv[j] = xv[j] + rv[j];
        }
        *(fx4*)(yout + gb + k4 * 4) = yv;
      }
    }
  }

#pragma unroll
  for (int m = 32; m >= 1; m >>= 1) lsum += __shfl_xor(lsum, m, 64);
  if (lane == 0) atomicAdd(lossacc, lsum * (1.25f / 4194304.f));  // 1.25/(N*D)
}

extern "C" void kernel_launch(void* const* d_in, const int* in_sizes, int n_in,
                              void* d_out, int out_size, void* d_ws, size_t ws_size,
                              hipStream_t stream) {
  const float* x = (const float*)d_in[0];     // [32768,128]
  const float* cbf = (const float*)d_in[1];   // [4,1024,128]
  float* y = (float*)d_out;
  float* lossout = y + (out_size - 1);
  u16* cbt = (u16*)d_ws;                      // 1 MiB k-major bf16 codebook

  rvq_prep<<<256, 64, 0, stream>>>(cbf, cbt, lossout);
  rvq_main<<<512, 256, 0, stream>>>(x, cbf, cbt, y, lossout);
}